// Round 6
// baseline (191.462 us; speedup 1.0000x reference)
//
#include <hip/hip_runtime.h>

#define OUTC 512
#define INC 512
#define SCAN_T 1024
#define NTILE 4
#define TCOL 128   // OUTC / NTILE

typedef __bf16 bf16x8 __attribute__((ext_vector_type(8)));
typedef float f32x4 __attribute__((ext_vector_type(4)));

static __device__ __forceinline__ unsigned short f2bf(float f) {
    unsigned u = __float_as_uint(f);
    unsigned r = u + 0x7fffu + ((u >> 16) & 1u);  // RNE
    return (unsigned short)(r >> 16);
}
static __device__ __forceinline__ float bflo(unsigned r) {
    return __uint_as_float(r << 16);
}
static __device__ __forceinline__ float bfhi(unsigned r) {
    return __uint_as_float(r & 0xffff0000u);
}

// ---------- fused prep: dst-count | X->bf16 | W->bf16^T | temb ----------
// grid = CB + XBB + 256 + OUTC blocks of 256 threads
__global__ __launch_bounds__(256) void k_prep(const float* __restrict__ x,
                                              const float* __restrict__ W,
                                              const float* __restrict__ t_emb,
                                              const float* __restrict__ Wt,
                                              const float* __restrict__ bt,
                                              const float* __restrict__ b,
                                              const int* __restrict__ dst,
                                              int* __restrict__ counts,
                                              unsigned short* __restrict__ xb,
                                              unsigned short* __restrict__ wtb,
                                              float* __restrict__ temb,
                                              int E, int CB, int XBB,
                                              int M, int Mpad, int TC) {
    __shared__ float smem[32 * 33];
    int bid = blockIdx.x;
    if (bid < CB) {
        // in-degree histogram
        int e = bid * 256 + threadIdx.x;
        if (e < E) atomicAdd(&counts[dst[e]], 1);
    } else if (bid < CB + XBB) {
        // X -> bf16 (zero-padded rows to Mpad); one thread per 8 elements
        int idx = (bid - CB) * 256 + threadIdx.x;
        int row = idx >> 6;
        int kg = (idx & 63) * 8;
        ushort4 h0 = make_ushort4(0, 0, 0, 0), h1 = make_ushort4(0, 0, 0, 0);
        if (row < M) {
            float4 v0 = *(const float4*)(x + (size_t)row * INC + kg);
            float4 v1 = *(const float4*)(x + (size_t)row * INC + kg + 4);
            h0 = make_ushort4(f2bf(v0.x), f2bf(v0.y), f2bf(v0.z), f2bf(v0.w));
            h1 = make_ushort4(f2bf(v1.x), f2bf(v1.y), f2bf(v1.z), f2bf(v1.w));
        }
        *(ushort4*)(xb + (size_t)row * INC + kg) = h0;
        *(ushort4*)(xb + (size_t)row * INC + kg + 4) = h1;
    } else if (bid < CB + XBB + 256) {
        // W[k][n] -> wtb[n][k] bf16, 32x32 tiles
        int b2 = bid - (CB + XBB);
        int bk = (b2 & 15) * 32, bn = (b2 >> 4) * 32;
        int tx = threadIdx.x & 31, ty = threadIdx.x >> 5;  // ty 0..7
        for (int r = ty; r < 32; r += 8)
            smem[r * 33 + tx] = W[(size_t)(bk + r) * OUTC + bn + tx];
        __syncthreads();
        for (int r = ty; r < 32; r += 8)
            wtb[(size_t)(bn + r) * INC + bk + tx] = f2bf(smem[tx * 33 + r]);
    } else {
        // temb[j] = t_emb @ Wt[:,j] + bt[j] + b[j]
        int j = bid - (CB + XBB + 256);
        int t = threadIdx.x;
        float p = 0.0f;
        for (int k = t; k < TC; k += 256) p += t_emb[k] * Wt[(size_t)k * OUTC + j];
        smem[t] = p;
        __syncthreads();
        for (int s = 128; s > 0; s >>= 1) {
            if (t < s) smem[t] += smem[t + s];
            __syncthreads();
        }
        if (t == 0) temb[j] = smem[0] + bt[j] + b[j];
    }
}

// ---------- scan + dinv fold (single block) ----------
__global__ __launch_bounds__(SCAN_T) void k_scan(const int* __restrict__ counts,
                                                 int* __restrict__ row_start,
                                                 int* __restrict__ cursor,
                                                 float* __restrict__ dinv, int N) {
    __shared__ int sums[SCAN_T];
    int t = threadIdx.x;
    int C = (N + SCAN_T - 1) / SCAN_T;
    int lo = t * C;
    int hi = lo + C; if (hi > N) hi = N; if (lo > N) lo = N;
    int s = 0;
    for (int i = lo; i < hi; ++i) s += counts[i];
    sums[t] = s;
    __syncthreads();
    for (int off = 1; off < SCAN_T; off <<= 1) {
        int v = (t >= off) ? sums[t - off] : 0;
        __syncthreads();
        sums[t] += v;
        __syncthreads();
    }
    int run = (t == 0) ? 0 : sums[t - 1];
    for (int i = lo; i < hi; ++i) {
        int c = counts[i];
        row_start[i] = run;
        cursor[i] = run;
        dinv[i] = rsqrtf((float)c + 1.0f);
        run += c;
    }
    if (hi == N) row_start[N] = run;
}

// ---------- fused scatter + MFMA GEMM ----------
// blocks [0,SB): CSR scatter.  blocks [SB, SB + (Mpad/128)*8): GEMM.
// GEMM: 256 threads = 4 waves, each wave a 32x64 tile of a 128x64 block tile,
// LDS-free direct global fragment loads, register double-buffered K pipeline.
// xwb output is column-tiled: [tile][Mpad][128] bf16.
__global__ __launch_bounds__(256) void k_sg(const int* __restrict__ src,
                                            const int* __restrict__ dst,
                                            int* __restrict__ cursor,
                                            int* __restrict__ esrc, int E, int SB,
                                            const unsigned short* __restrict__ xb,
                                            const unsigned short* __restrict__ wtb,
                                            unsigned short* __restrict__ xwb, int Mpad) {
    int bid = blockIdx.x;
    if (bid < SB) {
        int e = bid * 256 + threadIdx.x;
        if (e < E) {
            int d = dst[e];
            int pos = atomicAdd(&cursor[d], 1);
            esrc[pos] = src[e];
        }
        return;
    }
    const int b2 = bid - SB;
    const int n0 = (b2 & 7) * 64;                 // 8 n-tiles fastest -> XCD-stable wtb stripe
    const int m0 = (b2 >> 3) * 128 + (threadIdx.x >> 6) * 32;
    const int lane = threadIdx.x & 63;
    const int l15 = lane & 15;
    const int k8 = (lane >> 4) * 8;

    const unsigned short* Ab = xb + (size_t)(m0 + l15) * INC + k8;
    const unsigned short* Bb = wtb + (size_t)(n0 + l15) * INC + k8;

    f32x4 acc[2][4];
#pragma unroll
    for (int t = 0; t < 2; ++t)
#pragma unroll
        for (int u = 0; u < 4; ++u)
            acc[t][u] = (f32x4){0.f, 0.f, 0.f, 0.f};

    bf16x8 aA[2], bA[4], aB[2], bB[4];
#pragma unroll
    for (int t = 0; t < 2; ++t) aA[t] = *(const bf16x8*)(Ab + (size_t)t * 16 * INC);
#pragma unroll
    for (int u = 0; u < 4; ++u) bA[u] = *(const bf16x8*)(Bb + (size_t)u * 16 * INC);

#pragma unroll
    for (int k0 = 0; k0 < INC; k0 += 64) {
        const int kn = k0 + 32;
#pragma unroll
        for (int t = 0; t < 2; ++t) aB[t] = *(const bf16x8*)(Ab + (size_t)t * 16 * INC + kn);
#pragma unroll
        for (int u = 0; u < 4; ++u) bB[u] = *(const bf16x8*)(Bb + (size_t)u * 16 * INC + kn);
#pragma unroll
        for (int u = 0; u < 4; ++u)
#pragma unroll
            for (int t = 0; t < 2; ++t)
                acc[t][u] = __builtin_amdgcn_mfma_f32_16x16x32_bf16(aA[t], bA[u], acc[t][u], 0, 0, 0);
        const int kn2 = (k0 + 64 < INC) ? k0 + 64 : 0;  // dummy reload on last iter
#pragma unroll
        for (int t = 0; t < 2; ++t) aA[t] = *(const bf16x8*)(Ab + (size_t)t * 16 * INC + kn2);
#pragma unroll
        for (int u = 0; u < 4; ++u) bA[u] = *(const bf16x8*)(Bb + (size_t)u * 16 * INC + kn2);
#pragma unroll
        for (int u = 0; u < 4; ++u)
#pragma unroll
            for (int t = 0; t < 2; ++t)
                acc[t][u] = __builtin_amdgcn_mfma_f32_16x16x32_bf16(aB[t], bB[u], acc[t][u], 0, 0, 0);
    }

    const int rbase = (lane >> 4) * 4;
#pragma unroll
    for (int t = 0; t < 2; ++t)
#pragma unroll
        for (int u = 0; u < 4; ++u) {
            int gcol = n0 + u * 16 + l15;
            unsigned short* p = xwb + (size_t)(gcol >> 7) * Mpad * TCOL + (gcol & 127);
#pragma unroll
            for (int r = 0; r < 4; ++r) {
                int grow = m0 + t * 16 + rbase + r;  // < Mpad (padded)
                p[(size_t)grow * TCOL] = f2bf(acc[t][u][r]);
            }
        }
}

// ---------- column-tiled CSR gather (unchanged from R5, control variable) ----------
__global__ __launch_bounds__(256) void k_gather(const int* __restrict__ esrc,
                                                const int* __restrict__ row_start,
                                                const unsigned short* __restrict__ XWT,
                                                const float* __restrict__ dinv,
                                                const float* __restrict__ temb,
                                                float* __restrict__ out, int N, int Mpad) {
    const int tile = blockIdx.y;
    const int node = blockIdx.x * 4 + (threadIdx.x >> 6);
    if (node >= N) return;
    const int lane = threadIdx.x & 63;
    const int c2 = lane * 2;
    const unsigned short* base = XWT + (size_t)tile * Mpad * TCOL + c2;
    const int gc = tile * TCOL + c2;

    const float di = dinv[node];
    float a0, a1;
    {
        unsigned r = *(const unsigned*)(base + (size_t)node * TCOL);
        float2 tv = *(const float2*)(temb + gc);
        float nd = di * di;
        a0 = tv.x + nd * bflo(r);
        a1 = tv.y + nd * bfhi(r);
    }

    const int s0 = row_start[node];
    const int s1 = row_start[node + 1];
    int i = s0;
    for (; i + 4 <= s1; i += 4) {
        int s[4]; float nn[4]; unsigned rr[4];
#pragma unroll
        for (int j = 0; j < 4; ++j) s[j] = esrc[i + j];
#pragma unroll
        for (int j = 0; j < 4; ++j) nn[j] = dinv[s[j]] * di;
#pragma unroll
        for (int j = 0; j < 4; ++j) rr[j] = *(const unsigned*)(base + (size_t)s[j] * TCOL);
#pragma unroll
        for (int j = 0; j < 4; ++j) {
            a0 += nn[j] * bflo(rr[j]);
            a1 += nn[j] * bfhi(rr[j]);
        }
    }
    for (; i < s1; ++i) {
        int s = esrc[i];
        float nrm = dinv[s] * di;
        unsigned r = *(const unsigned*)(base + (size_t)s * TCOL);
        a0 += nrm * bflo(r);
        a1 += nrm * bfhi(r);
    }

    *(float2*)(out + (size_t)node * OUTC + gc) = make_float2(a0, a1);
}

extern "C" void kernel_launch(void* const* d_in, const int* in_sizes, int n_in,
                              void* d_out, int out_size, void* d_ws, size_t ws_size,
                              hipStream_t stream) {
    const float* x     = (const float*)d_in[0];
    const float* t_emb = (const float*)d_in[1];
    const int*   ei    = (const int*)d_in[2];
    const float* W     = (const float*)d_in[3];
    const float* b     = (const float*)d_in[4];
    const float* Wt    = (const float*)d_in[5];
    const float* bt    = (const float*)d_in[6];
    float* out = (float*)d_out;

    const int N  = in_sizes[0] / INC;    // 10000
    const int E  = in_sizes[2] / 2;      // 160000
    const int TC = in_sizes[1];          // 256
    const int Mpad = (N + 127) & ~127;   // 10112

    char* ws = (char*)d_ws;
    size_t off = 0;
    unsigned short* xb  = (unsigned short*)(ws + off); off += (size_t)Mpad * INC * 2;
    unsigned short* xwb = (unsigned short*)(ws + off); off += (size_t)Mpad * OUTC * 2;
    unsigned short* wtb = (unsigned short*)(ws + off); off += (size_t)INC * OUTC * 2;
    float* dinv = (float*)(ws + off);      off += ((size_t)N * 4 + 255) & ~(size_t)255;
    int* counts = (int*)(ws + off);        off += ((size_t)N * 4 + 255) & ~(size_t)255;
    int* row_start = (int*)(ws + off);     off += ((size_t)(N + 1) * 4 + 255) & ~(size_t)255;
    int* cursor = (int*)(ws + off);        off += ((size_t)N * 4 + 255) & ~(size_t)255;
    int* esrc = (int*)(ws + off);          off += ((size_t)E * 4 + 255) & ~(size_t)255;
    float* temb = (float*)(ws + off);      off += OUTC * 4;

    const int* srcIdx = ei;
    const int* dstIdx = ei + E;

    const int CB  = (E + 255) / 256;        // 625 count/scatter blocks
    const int XBB = Mpad * (INC / 8) / 256; // 2528 xb-convert blocks

    hipMemsetAsync(counts, 0, (size_t)N * sizeof(int), stream);
    k_prep<<<CB + XBB + 256 + OUTC, 256, 0, stream>>>(x, W, t_emb, Wt, bt, b, dstIdx,
                                                      counts, xb, wtb, temb,
                                                      E, CB, XBB, N, Mpad, TC);
    k_scan<<<1, SCAN_T, 0, stream>>>(counts, row_start, cursor, dinv, N);
    k_sg<<<CB + (Mpad / 128) * 8, 256, 0, stream>>>(srcIdx, dstIdx, cursor, esrc, E, CB,
                                                    xb, wtb, xwb, Mpad);
    dim3 gather_grid((N + 3) / 4, NTILE);
    k_gather<<<gather_grid, 256, 0, stream>>>(esrc, row_start, xwb, dinv, temb, out, N, Mpad);
}

// Round 7
// 166.377 us; speedup vs baseline: 1.1508x; 1.1508x over previous
//
#include <hip/hip_runtime.h>

#define OUTC 512
#define INC 512
#define SCAN_T 1024
#define NTILE 4
#define TCOL 128   // OUTC / NTILE
#define LDA 72     // 64 + 8 ushort pad: conflict-free ds_read_b128 (rows 0-7 span all 32 banks)

typedef __bf16 bf16x8 __attribute__((ext_vector_type(8)));
typedef float f32x4 __attribute__((ext_vector_type(4)));

static __device__ __forceinline__ unsigned short f2bf(float f) {
    unsigned u = __float_as_uint(f);
    unsigned r = u + 0x7fffu + ((u >> 16) & 1u);  // RNE
    return (unsigned short)(r >> 16);
}
static __device__ __forceinline__ float bflo(unsigned r) {
    return __uint_as_float(r << 16);
}
static __device__ __forceinline__ float bfhi(unsigned r) {
    return __uint_as_float(r & 0xffff0000u);
}

// ---------- fused prep: dst-count | X->bf16 | W->bf16^T | temb ----------
__global__ __launch_bounds__(256) void k_prep(const float* __restrict__ x,
                                              const float* __restrict__ W,
                                              const float* __restrict__ t_emb,
                                              const float* __restrict__ Wt,
                                              const float* __restrict__ bt,
                                              const float* __restrict__ b,
                                              const int* __restrict__ dst,
                                              int* __restrict__ counts,
                                              unsigned short* __restrict__ xb,
                                              unsigned short* __restrict__ wtb,
                                              float* __restrict__ temb,
                                              int E, int CB, int XBB,
                                              int M, int Mpad, int TC) {
    __shared__ float smem[32 * 33];
    int bid = blockIdx.x;
    if (bid < CB) {
        int e = bid * 256 + threadIdx.x;
        if (e < E) atomicAdd(&counts[dst[e]], 1);
    } else if (bid < CB + XBB) {
        int idx = (bid - CB) * 256 + threadIdx.x;
        int row = idx >> 6;
        int kg = (idx & 63) * 8;
        ushort4 h0 = make_ushort4(0, 0, 0, 0), h1 = make_ushort4(0, 0, 0, 0);
        if (row < M) {
            float4 v0 = *(const float4*)(x + (size_t)row * INC + kg);
            float4 v1 = *(const float4*)(x + (size_t)row * INC + kg + 4);
            h0 = make_ushort4(f2bf(v0.x), f2bf(v0.y), f2bf(v0.z), f2bf(v0.w));
            h1 = make_ushort4(f2bf(v1.x), f2bf(v1.y), f2bf(v1.z), f2bf(v1.w));
        }
        *(ushort4*)(xb + (size_t)row * INC + kg) = h0;
        *(ushort4*)(xb + (size_t)row * INC + kg + 4) = h1;
    } else if (bid < CB + XBB + 256) {
        int b2 = bid - (CB + XBB);
        int bk = (b2 & 15) * 32, bn = (b2 >> 4) * 32;
        int tx = threadIdx.x & 31, ty = threadIdx.x >> 5;
        for (int r = ty; r < 32; r += 8)
            smem[r * 33 + tx] = W[(size_t)(bk + r) * OUTC + bn + tx];
        __syncthreads();
        for (int r = ty; r < 32; r += 8)
            wtb[(size_t)(bn + r) * INC + bk + tx] = f2bf(smem[tx * 33 + r]);
    } else {
        int j = bid - (CB + XBB + 256);
        int t = threadIdx.x;
        float p = 0.0f;
        for (int k = t; k < TC; k += 256) p += t_emb[k] * Wt[(size_t)k * OUTC + j];
        smem[t] = p;
        __syncthreads();
        for (int s = 128; s > 0; s >>= 1) {
            if (t < s) smem[t] += smem[t + s];
            __syncthreads();
        }
        if (t == 0) temb[j] = smem[0] + bt[j] + b[j];
    }
}

// ---------- scan + dinv fold ----------
__global__ __launch_bounds__(SCAN_T) void k_scan(const int* __restrict__ counts,
                                                 int* __restrict__ row_start,
                                                 int* __restrict__ cursor,
                                                 float* __restrict__ dinv, int N) {
    __shared__ int sums[SCAN_T];
    int t = threadIdx.x;
    int C = (N + SCAN_T - 1) / SCAN_T;
    int lo = t * C;
    int hi = lo + C; if (hi > N) hi = N; if (lo > N) lo = N;
    int s = 0;
    for (int i = lo; i < hi; ++i) s += counts[i];
    sums[t] = s;
    __syncthreads();
    for (int off = 1; off < SCAN_T; off <<= 1) {
        int v = (t >= off) ? sums[t - off] : 0;
        __syncthreads();
        sums[t] += v;
        __syncthreads();
    }
    int run = (t == 0) ? 0 : sums[t - 1];
    for (int i = lo; i < hi; ++i) {
        int c = counts[i];
        row_start[i] = run;
        cursor[i] = run;
        dinv[i] = rsqrtf((float)c + 1.0f);
        run += c;
    }
    if (hi == N) row_start[N] = run;
}

// ---------- CSR scatter ----------
__global__ void k_scatter(const int* __restrict__ src, const int* __restrict__ dst,
                          int* __restrict__ cursor, int* __restrict__ esrc, int E) {
    int e = blockIdx.x * blockDim.x + threadIdx.x;
    if (e < E) {
        int d = dst[e];
        int pos = atomicAdd(&cursor[d], 1);
        esrc[pos] = src[e];
    }
}

// ---------- LDS-staged MFMA GEMM: 128x64 tile, BK=64, 4 waves ----------
// grid: 632 blocks, n-tile in low 3 bits (XCD-stable wtb stripe)
// output xwb column-tiled [tile][Mpad][128] bf16
__global__ __launch_bounds__(256) void k_gemm(const unsigned short* __restrict__ xb,
                                              const unsigned short* __restrict__ wtb,
                                              unsigned short* __restrict__ xwb, int Mpad) {
    __shared__ unsigned short la[128 * LDA];
    __shared__ unsigned short lb[64 * LDA];

    const int bid = blockIdx.x;
    const int n0 = (bid & 7) * 64;
    const int m0 = (bid >> 3) * 128;
    const int tid = threadIdx.x;
    const int lane = tid & 63;
    const int wave = tid >> 6;
    const int wm = wave * 32;
    const int l15 = lane & 15;
    const int k8 = (lane >> 4) * 8;

    f32x4 acc[2][4];
#pragma unroll
    for (int t = 0; t < 2; ++t)
#pragma unroll
        for (int u = 0; u < 4; ++u)
            acc[t][u] = (f32x4){0.f, 0.f, 0.f, 0.f};

    for (int k0 = 0; k0 < INC; k0 += 64) {
        // stage A: 128 rows x 64 k = 1024 chunks of 8 ushorts; 4 per thread
#pragma unroll
        for (int i = 0; i < 4; ++i) {
            int f = i * 256 + tid;
            int row = f >> 3, c = f & 7;
            uint4 v = *(const uint4*)(xb + (size_t)(m0 + row) * INC + k0 + c * 8);
            *(uint4*)(&la[row * LDA + c * 8]) = v;
        }
        // stage B: 64 rows x 64 k = 512 chunks; 2 per thread
#pragma unroll
        for (int i = 0; i < 2; ++i) {
            int f = i * 256 + tid;
            int row = f >> 3, c = f & 7;
            uint4 v = *(const uint4*)(wtb + (size_t)(n0 + row) * INC + k0 + c * 8);
            *(uint4*)(&lb[row * LDA + c * 8]) = v;
        }
        __syncthreads();

#pragma unroll
        for (int kc = 0; kc < 64; kc += 32) {
            bf16x8 af0 = *(const bf16x8*)(&la[(wm + l15) * LDA + kc + k8]);
            bf16x8 af1 = *(const bf16x8*)(&la[(wm + 16 + l15) * LDA + kc + k8]);
#pragma unroll
            for (int u = 0; u < 4; ++u) {
                bf16x8 bfr = *(const bf16x8*)(&lb[(u * 16 + l15) * LDA + kc + k8]);
                acc[0][u] = __builtin_amdgcn_mfma_f32_16x16x32_bf16(af0, bfr, acc[0][u], 0, 0, 0);
                acc[1][u] = __builtin_amdgcn_mfma_f32_16x16x32_bf16(af1, bfr, acc[1][u], 0, 0, 0);
            }
        }
        __syncthreads();
    }

    const int rbase = (lane >> 4) * 4;
#pragma unroll
    for (int t = 0; t < 2; ++t)
#pragma unroll
        for (int u = 0; u < 4; ++u) {
            int gcol = n0 + u * 16 + l15;
            unsigned short* p = xwb + (size_t)(gcol >> 7) * Mpad * TCOL + (gcol & 127);
#pragma unroll
            for (int r = 0; r < 4; ++r) {
                int grow = m0 + wm + t * 16 + rbase + r;  // < Mpad (padded)
                p[(size_t)grow * TCOL] = f2bf(acc[t][u][r]);
            }
        }
}

// ---------- column-tiled CSR gather, unroll 8, di factored out ----------
__global__ __launch_bounds__(256) void k_gather(const int* __restrict__ esrc,
                                                const int* __restrict__ row_start,
                                                const unsigned short* __restrict__ XWT,
                                                const float* __restrict__ dinv,
                                                const float* __restrict__ temb,
                                                float* __restrict__ out, int N, int Mpad) {
    const int tile = blockIdx.y;
    const int node = blockIdx.x * 4 + (threadIdx.x >> 6);
    if (node >= N) return;
    const int lane = threadIdx.x & 63;
    const int c2 = lane * 2;
    const unsigned short* base = XWT + (size_t)tile * Mpad * TCOL + c2;
    const int gc = tile * TCOL + c2;

    const float di = dinv[node];
    // accumulate Sum(dinv[s]*xw[s]) + di*xw[node]; multiply by di at the end
    float a0, a1;
    {
        unsigned r = *(const unsigned*)(base + (size_t)node * TCOL);
        a0 = di * bflo(r);
        a1 = di * bfhi(r);
    }

    const int s0 = row_start[node];
    const int s1 = row_start[node + 1];
    int i = s0;
    for (; i + 8 <= s1; i += 8) {
        int s[8]; float nn[8]; unsigned rr[8];
#pragma unroll
        for (int j = 0; j < 8; ++j) s[j] = esrc[i + j];
#pragma unroll
        for (int j = 0; j < 8; ++j) nn[j] = dinv[s[j]];
#pragma unroll
        for (int j = 0; j < 8; ++j) rr[j] = *(const unsigned*)(base + (size_t)s[j] * TCOL);
#pragma unroll
        for (int j = 0; j < 8; ++j) {
            a0 += nn[j] * bflo(rr[j]);
            a1 += nn[j] * bfhi(rr[j]);
        }
    }
    for (; i < s1; ++i) {
        int s = esrc[i];
        float nrm = dinv[s];
        unsigned r = *(const unsigned*)(base + (size_t)s * TCOL);
        a0 += nrm * bflo(r);
        a1 += nrm * bfhi(r);
    }

    float2 tv = *(const float2*)(temb + gc);
    *(float2*)(out + (size_t)node * OUTC + gc) = make_float2(di * a0 + tv.x, di * a1 + tv.y);
}

extern "C" void kernel_launch(void* const* d_in, const int* in_sizes, int n_in,
                              void* d_out, int out_size, void* d_ws, size_t ws_size,
                              hipStream_t stream) {
    const float* x     = (const float*)d_in[0];
    const float* t_emb = (const float*)d_in[1];
    const int*   ei    = (const int*)d_in[2];
    const float* W     = (const float*)d_in[3];
    const float* b     = (const float*)d_in[4];
    const float* Wt    = (const float*)d_in[5];
    const float* bt    = (const float*)d_in[6];
    float* out = (float*)d_out;

    const int N  = in_sizes[0] / INC;    // 10000
    const int E  = in_sizes[2] / 2;      // 160000
    const int TC = in_sizes[1];          // 256
    const int Mpad = (N + 127) & ~127;   // 10112

    char* ws = (char*)d_ws;
    size_t off = 0;
    unsigned short* xb  = (unsigned short*)(ws + off); off += (size_t)Mpad * INC * 2;
    unsigned short* xwb = (unsigned short*)(ws + off); off += (size_t)Mpad * OUTC * 2;
    unsigned short* wtb = (unsigned short*)(ws + off); off += (size_t)INC * OUTC * 2;
    float* dinv = (float*)(ws + off);      off += ((size_t)N * 4 + 255) & ~(size_t)255;
    int* counts = (int*)(ws + off);        off += ((size_t)N * 4 + 255) & ~(size_t)255;
    int* row_start = (int*)(ws + off);     off += ((size_t)(N + 1) * 4 + 255) & ~(size_t)255;
    int* cursor = (int*)(ws + off);        off += ((size_t)N * 4 + 255) & ~(size_t)255;
    int* esrc = (int*)(ws + off);          off += ((size_t)E * 4 + 255) & ~(size_t)255;
    float* temb = (float*)(ws + off);      off += OUTC * 4;

    const int* srcIdx = ei;
    const int* dstIdx = ei + E;

    const int CB  = (E + 255) / 256;
    const int XBB = Mpad * (INC / 8) / 256;

    hipMemsetAsync(counts, 0, (size_t)N * sizeof(int), stream);
    k_prep<<<CB + XBB + 256 + OUTC, 256, 0, stream>>>(x, W, t_emb, Wt, bt, b, dstIdx,
                                                      counts, xb, wtb, temb,
                                                      E, CB, XBB, N, Mpad, TC);
    k_scan<<<1, SCAN_T, 0, stream>>>(counts, row_start, cursor, dinv, N);
    k_scatter<<<(E + 255) / 256, 256, 0, stream>>>(srcIdx, dstIdx, cursor, esrc, E);
    k_gemm<<<(Mpad / 128) * 8, 256, 0, stream>>>(xb, wtb, xwb, Mpad);
    dim3 gather_grid((N + 3) / 4, NTILE);
    k_gather<<<gather_grid, 256, 0, stream>>>(esrc, row_start, xwb, dinv, temb, out, N, Mpad);
}

// Round 8
// 165.812 us; speedup vs baseline: 1.1547x; 1.0034x over previous
//
#include <hip/hip_runtime.h>

#define OUTC 512
#define INC 512
#define SCAN_T 1024
#define NTILE 4
#define TCOL 128   // OUTC / NTILE
#define LDA 72     // 64 + 8 ushort pad: conflict-free ds_read_b128 (rows 0-7 span all 32 banks)

typedef __bf16 bf16x8 __attribute__((ext_vector_type(8)));
typedef float f32x4 __attribute__((ext_vector_type(4)));

static __device__ __forceinline__ unsigned short f2bf(float f) {
    unsigned u = __float_as_uint(f);
    unsigned r = u + 0x7fffu + ((u >> 16) & 1u);  // RNE
    return (unsigned short)(r >> 16);
}
static __device__ __forceinline__ float bflo(unsigned r) {
    return __uint_as_float(r << 16);
}
static __device__ __forceinline__ float bfhi(unsigned r) {
    return __uint_as_float(r & 0xffff0000u);
}

// ---------- fused prep: dst-count | X->bf16 | W->bf16^T | temb ----------
__global__ __launch_bounds__(256) void k_prep(const float* __restrict__ x,
                                              const float* __restrict__ W,
                                              const float* __restrict__ t_emb,
                                              const float* __restrict__ Wt,
                                              const float* __restrict__ bt,
                                              const float* __restrict__ b,
                                              const int* __restrict__ dst,
                                              int* __restrict__ counts,
                                              unsigned short* __restrict__ xb,
                                              unsigned short* __restrict__ wtb,
                                              float* __restrict__ temb,
                                              int E, int CB, int XBB,
                                              int M, int Mpad, int TC) {
    __shared__ float smem[32 * 33];
    int bid = blockIdx.x;
    if (bid < CB) {
        int e = bid * 256 + threadIdx.x;
        if (e < E) atomicAdd(&counts[dst[e]], 1);
    } else if (bid < CB + XBB) {
        int idx = (bid - CB) * 256 + threadIdx.x;
        int row = idx >> 6;
        int kg = (idx & 63) * 8;
        ushort4 h0 = make_ushort4(0, 0, 0, 0), h1 = make_ushort4(0, 0, 0, 0);
        if (row < M) {
            float4 v0 = *(const float4*)(x + (size_t)row * INC + kg);
            float4 v1 = *(const float4*)(x + (size_t)row * INC + kg + 4);
            h0 = make_ushort4(f2bf(v0.x), f2bf(v0.y), f2bf(v0.z), f2bf(v0.w));
            h1 = make_ushort4(f2bf(v1.x), f2bf(v1.y), f2bf(v1.z), f2bf(v1.w));
        }
        *(ushort4*)(xb + (size_t)row * INC + kg) = h0;
        *(ushort4*)(xb + (size_t)row * INC + kg + 4) = h1;
    } else if (bid < CB + XBB + 256) {
        int b2 = bid - (CB + XBB);
        int bk = (b2 & 15) * 32, bn = (b2 >> 4) * 32;
        int tx = threadIdx.x & 31, ty = threadIdx.x >> 5;
        for (int r = ty; r < 32; r += 8)
            smem[r * 33 + tx] = W[(size_t)(bk + r) * OUTC + bn + tx];
        __syncthreads();
        for (int r = ty; r < 32; r += 8)
            wtb[(size_t)(bn + r) * INC + bk + tx] = f2bf(smem[tx * 33 + r]);
    } else {
        int j = bid - (CB + XBB + 256);
        int t = threadIdx.x;
        float p = 0.0f;
        for (int k = t; k < TC; k += 256) p += t_emb[k] * Wt[(size_t)k * OUTC + j];
        smem[t] = p;
        __syncthreads();
        for (int s = 128; s > 0; s >>= 1) {
            if (t < s) smem[t] += smem[t + s];
            __syncthreads();
        }
        if (t == 0) temb[j] = smem[0] + bt[j] + b[j];
    }
}

// ---------- scan + dinv fold ----------
__global__ __launch_bounds__(SCAN_T) void k_scan(const int* __restrict__ counts,
                                                 int* __restrict__ row_start,
                                                 int* __restrict__ cursor,
                                                 float* __restrict__ dinv, int N) {
    __shared__ int sums[SCAN_T];
    int t = threadIdx.x;
    int C = (N + SCAN_T - 1) / SCAN_T;
    int lo = t * C;
    int hi = lo + C; if (hi > N) hi = N; if (lo > N) lo = N;
    int s = 0;
    for (int i = lo; i < hi; ++i) s += counts[i];
    sums[t] = s;
    __syncthreads();
    for (int off = 1; off < SCAN_T; off <<= 1) {
        int v = (t >= off) ? sums[t - off] : 0;
        __syncthreads();
        sums[t] += v;
        __syncthreads();
    }
    int run = (t == 0) ? 0 : sums[t - 1];
    for (int i = lo; i < hi; ++i) {
        int c = counts[i];
        row_start[i] = run;
        cursor[i] = run;
        dinv[i] = rsqrtf((float)c + 1.0f);
        run += c;
    }
    if (hi == N) row_start[N] = run;
}

// ---------- CSR scatter ----------
__global__ void k_scatter(const int* __restrict__ src, const int* __restrict__ dst,
                          int* __restrict__ cursor, int* __restrict__ esrc, int E) {
    int e = blockIdx.x * blockDim.x + threadIdx.x;
    if (e < E) {
        int d = dst[e];
        int pos = atomicAdd(&cursor[d], 1);
        esrc[pos] = src[e];
    }
}

// ---------- LDS-staged MFMA GEMM: 128x64 tile, BK=64, 4 waves ----------
// n-tile in low 3 bits -> XCD j owns n-tile j (wtb stripe + xwb col-tile affinity)
__global__ __launch_bounds__(256) void k_gemm(const unsigned short* __restrict__ xb,
                                              const unsigned short* __restrict__ wtb,
                                              unsigned short* __restrict__ xwb, int Mpad) {
    __shared__ unsigned short la[128 * LDA];
    __shared__ unsigned short lb[64 * LDA];

    const int bid = blockIdx.x;
    const int n0 = (bid & 7) * 64;
    const int m0 = (bid >> 3) * 128;
    const int tid = threadIdx.x;
    const int lane = tid & 63;
    const int wave = tid >> 6;
    const int wm = wave * 32;
    const int l15 = lane & 15;
    const int k8 = (lane >> 4) * 8;

    f32x4 acc[2][4];
#pragma unroll
    for (int t = 0; t < 2; ++t)
#pragma unroll
        for (int u = 0; u < 4; ++u)
            acc[t][u] = (f32x4){0.f, 0.f, 0.f, 0.f};

    for (int k0 = 0; k0 < INC; k0 += 64) {
#pragma unroll
        for (int i = 0; i < 4; ++i) {
            int f = i * 256 + tid;
            int row = f >> 3, c = f & 7;
            uint4 v = *(const uint4*)(xb + (size_t)(m0 + row) * INC + k0 + c * 8);
            *(uint4*)(&la[row * LDA + c * 8]) = v;
        }
#pragma unroll
        for (int i = 0; i < 2; ++i) {
            int f = i * 256 + tid;
            int row = f >> 3, c = f & 7;
            uint4 v = *(const uint4*)(wtb + (size_t)(n0 + row) * INC + k0 + c * 8);
            *(uint4*)(&lb[row * LDA + c * 8]) = v;
        }
        __syncthreads();

#pragma unroll
        for (int kc = 0; kc < 64; kc += 32) {
            bf16x8 af0 = *(const bf16x8*)(&la[(wm + l15) * LDA + kc + k8]);
            bf16x8 af1 = *(const bf16x8*)(&la[(wm + 16 + l15) * LDA + kc + k8]);
#pragma unroll
            for (int u = 0; u < 4; ++u) {
                bf16x8 bfr = *(const bf16x8*)(&lb[(u * 16 + l15) * LDA + kc + k8]);
                acc[0][u] = __builtin_amdgcn_mfma_f32_16x16x32_bf16(af0, bfr, acc[0][u], 0, 0, 0);
                acc[1][u] = __builtin_amdgcn_mfma_f32_16x16x32_bf16(af1, bfr, acc[1][u], 0, 0, 0);
            }
        }
        __syncthreads();
    }

    const int rbase = (lane >> 4) * 4;
#pragma unroll
    for (int t = 0; t < 2; ++t)
#pragma unroll
        for (int u = 0; u < 4; ++u) {
            int gcol = n0 + u * 16 + l15;
            unsigned short* p = xwb + (size_t)(gcol >> 7) * Mpad * TCOL + (gcol & 127);
#pragma unroll
            for (int r = 0; r < 4; ++r) {
                int grow = m0 + wm + t * 16 + rbase + r;  // < Mpad (padded)
                p[(size_t)grow * TCOL] = f2bf(acc[t][u][r]);
            }
        }
}

// ---------- XCD-pinned column-tiled CSR gather ----------
// flat grid; tile = (bid&7)>>1 so XCD pair {2t,2t+1} serves ONLY tile t
// (2.6 MB < 4 MB L2 -> resident; also matches gemm's writer XCDs).
// per 8 bids: 2 bids/tile x 4 waves = nodes [ng*8, ng*8+8) for each tile.
__global__ __launch_bounds__(256) void k_gather(const int* __restrict__ esrc,
                                                const int* __restrict__ row_start,
                                                const unsigned short* __restrict__ XWT,
                                                const float* __restrict__ dinv,
                                                const float* __restrict__ temb,
                                                float* __restrict__ out, int N, int Mpad) {
    const int bid = blockIdx.x;
    const int tile = (bid & 7) >> 1;
    const int node = (bid >> 3) * 8 + (bid & 1) * 4 + (threadIdx.x >> 6);
    if (node >= N) return;
    const int lane = threadIdx.x & 63;
    const int c2 = lane * 2;
    const unsigned short* base = XWT + (size_t)tile * Mpad * TCOL + c2;
    const int gc = tile * TCOL + c2;

    const float di = dinv[node];
    float a0, a1;
    {
        unsigned r = *(const unsigned*)(base + (size_t)node * TCOL);
        a0 = di * bflo(r);
        a1 = di * bfhi(r);
    }

    const int s0 = row_start[node];
    const int s1 = row_start[node + 1];
    int i = s0;
    for (; i + 8 <= s1; i += 8) {
        int s[8]; float nn[8]; unsigned rr[8];
#pragma unroll
        for (int j = 0; j < 8; ++j) s[j] = esrc[i + j];
#pragma unroll
        for (int j = 0; j < 8; ++j) nn[j] = dinv[s[j]];
#pragma unroll
        for (int j = 0; j < 8; ++j) rr[j] = *(const unsigned*)(base + (size_t)s[j] * TCOL);
#pragma unroll
        for (int j = 0; j < 8; ++j) {
            a0 += nn[j] * bflo(rr[j]);
            a1 += nn[j] * bfhi(rr[j]);
        }
    }
    for (; i < s1; ++i) {
        int s = esrc[i];
        float nrm = dinv[s];
        unsigned r = *(const unsigned*)(base + (size_t)s * TCOL);
        a0 += nrm * bflo(r);
        a1 += nrm * bfhi(r);
    }

    float2 tv = *(const float2*)(temb + gc);
    *(float2*)(out + (size_t)node * OUTC + gc) = make_float2(di * a0 + tv.x, di * a1 + tv.y);
}

extern "C" void kernel_launch(void* const* d_in, const int* in_sizes, int n_in,
                              void* d_out, int out_size, void* d_ws, size_t ws_size,
                              hipStream_t stream) {
    const float* x     = (const float*)d_in[0];
    const float* t_emb = (const float*)d_in[1];
    const int*   ei    = (const int*)d_in[2];
    const float* W     = (const float*)d_in[3];
    const float* b     = (const float*)d_in[4];
    const float* Wt    = (const float*)d_in[5];
    const float* bt    = (const float*)d_in[6];
    float* out = (float*)d_out;

    const int N  = in_sizes[0] / INC;    // 10000
    const int E  = in_sizes[2] / 2;      // 160000
    const int TC = in_sizes[1];          // 256
    const int Mpad = (N + 127) & ~127;   // 10112

    char* ws = (char*)d_ws;
    size_t off = 0;
    unsigned short* xb  = (unsigned short*)(ws + off); off += (size_t)Mpad * INC * 2;
    unsigned short* xwb = (unsigned short*)(ws + off); off += (size_t)Mpad * OUTC * 2;
    unsigned short* wtb = (unsigned short*)(ws + off); off += (size_t)INC * OUTC * 2;
    float* dinv = (float*)(ws + off);      off += ((size_t)N * 4 + 255) & ~(size_t)255;
    int* counts = (int*)(ws + off);        off += ((size_t)N * 4 + 255) & ~(size_t)255;
    int* row_start = (int*)(ws + off);     off += ((size_t)(N + 1) * 4 + 255) & ~(size_t)255;
    int* cursor = (int*)(ws + off);        off += ((size_t)N * 4 + 255) & ~(size_t)255;
    int* esrc = (int*)(ws + off);          off += ((size_t)E * 4 + 255) & ~(size_t)255;
    float* temb = (float*)(ws + off);      off += OUTC * 4;

    const int* srcIdx = ei;
    const int* dstIdx = ei + E;

    const int CB  = (E + 255) / 256;
    const int XBB = Mpad * (INC / 8) / 256;

    hipMemsetAsync(counts, 0, (size_t)N * sizeof(int), stream);
    k_prep<<<CB + XBB + 256 + OUTC, 256, 0, stream>>>(x, W, t_emb, Wt, bt, b, dstIdx,
                                                      counts, xb, wtb, temb,
                                                      E, CB, XBB, N, Mpad, TC);
    k_scan<<<1, SCAN_T, 0, stream>>>(counts, row_start, cursor, dinv, N);
    k_scatter<<<(E + 255) / 256, 256, 0, stream>>>(srcIdx, dstIdx, cursor, esrc, E);
    k_gemm<<<(Mpad / 128) * 8, 256, 0, stream>>>(xb, wtb, xwb, Mpad);

    const int gather_blocks = ((N + 7) / 8) * 8;  // 8 bids cover 8 nodes x 4 tiles
    k_gather<<<gather_blocks, 256, 0, stream>>>(esrc, row_start, xwb, dinv, temb, out, N, Mpad);
}

// Round 9
// 161.715 us; speedup vs baseline: 1.1840x; 1.0253x over previous
//
#include <hip/hip_runtime.h>

#define OUTC 512
#define INC 512
#define SCAN_T 1024
#define NTILE 4
#define TCOL 128   // OUTC / NTILE
#define LDA 72     // 64 + 8 ushort pad: conflict-free ds_read_b128

typedef __bf16 bf16x8 __attribute__((ext_vector_type(8)));
typedef float f32x4 __attribute__((ext_vector_type(4)));

static __device__ __forceinline__ unsigned short f2bf(float f) {
    unsigned u = __float_as_uint(f);
    unsigned r = u + 0x7fffu + ((u >> 16) & 1u);  // RNE
    return (unsigned short)(r >> 16);
}
static __device__ __forceinline__ float bflo(unsigned r) {
    return __uint_as_float(r << 16);
}
static __device__ __forceinline__ float bfhi(unsigned r) {
    return __uint_as_float(r & 0xffff0000u);
}

// ---------- fused prep: dst-count | X->bf16 | W->bf16^T | temb ----------
__global__ __launch_bounds__(256) void k_prep(const float* __restrict__ x,
                                              const float* __restrict__ W,
                                              const float* __restrict__ t_emb,
                                              const float* __restrict__ Wt,
                                              const float* __restrict__ bt,
                                              const float* __restrict__ b,
                                              const int* __restrict__ dst,
                                              int* __restrict__ counts,
                                              unsigned short* __restrict__ xb,
                                              unsigned short* __restrict__ wtb,
                                              float* __restrict__ temb,
                                              int E, int CB, int XBB,
                                              int M, int Mpad, int TC) {
    __shared__ float smem[32 * 33];
    int bid = blockIdx.x;
    if (bid < CB) {
        int e = bid * 256 + threadIdx.x;
        if (e < E) atomicAdd(&counts[dst[e]], 1);
    } else if (bid < CB + XBB) {
        int idx = (bid - CB) * 256 + threadIdx.x;
        int row = idx >> 6;
        int kg = (idx & 63) * 8;
        ushort4 h0 = make_ushort4(0, 0, 0, 0), h1 = make_ushort4(0, 0, 0, 0);
        if (row < M) {
            float4 v0 = *(const float4*)(x + (size_t)row * INC + kg);
            float4 v1 = *(const float4*)(x + (size_t)row * INC + kg + 4);
            h0 = make_ushort4(f2bf(v0.x), f2bf(v0.y), f2bf(v0.z), f2bf(v0.w));
            h1 = make_ushort4(f2bf(v1.x), f2bf(v1.y), f2bf(v1.z), f2bf(v1.w));
        }
        *(ushort4*)(xb + (size_t)row * INC + kg) = h0;
        *(ushort4*)(xb + (size_t)row * INC + kg + 4) = h1;
    } else if (bid < CB + XBB + 256) {
        int b2 = bid - (CB + XBB);
        int bk = (b2 & 15) * 32, bn = (b2 >> 4) * 32;
        int tx = threadIdx.x & 31, ty = threadIdx.x >> 5;
        for (int r = ty; r < 32; r += 8)
            smem[r * 33 + tx] = W[(size_t)(bk + r) * OUTC + bn + tx];
        __syncthreads();
        for (int r = ty; r < 32; r += 8)
            wtb[(size_t)(bn + r) * INC + bk + tx] = f2bf(smem[tx * 33 + r]);
    } else {
        int j = bid - (CB + XBB + 256);
        int t = threadIdx.x;
        float p = 0.0f;
        for (int k = t; k < TC; k += 256) p += t_emb[k] * Wt[(size_t)k * OUTC + j];
        smem[t] = p;
        __syncthreads();
        for (int s = 128; s > 0; s >>= 1) {
            if (t < s) smem[t] += smem[t + s];
            __syncthreads();
        }
        if (t == 0) temb[j] = smem[0] + bt[j] + b[j];
    }
}

// ---------- scan + dinv fold ----------
__global__ __launch_bounds__(SCAN_T) void k_scan(const int* __restrict__ counts,
                                                 int* __restrict__ row_start,
                                                 int* __restrict__ cursor,
                                                 float* __restrict__ dinv, int N) {
    __shared__ int sums[SCAN_T];
    int t = threadIdx.x;
    int C = (N + SCAN_T - 1) / SCAN_T;
    int lo = t * C;
    int hi = lo + C; if (hi > N) hi = N; if (lo > N) lo = N;
    int s = 0;
    for (int i = lo; i < hi; ++i) s += counts[i];
    sums[t] = s;
    __syncthreads();
    for (int off = 1; off < SCAN_T; off <<= 1) {
        int v = (t >= off) ? sums[t - off] : 0;
        __syncthreads();
        sums[t] += v;
        __syncthreads();
    }
    int run = (t == 0) ? 0 : sums[t - 1];
    for (int i = lo; i < hi; ++i) {
        int c = counts[i];
        row_start[i] = run;
        cursor[i] = run;
        dinv[i] = rsqrtf((float)c + 1.0f);
        run += c;
    }
    if (hi == N) row_start[N] = run;
}

// ---------- CSR scatter ----------
__global__ void k_scatter(const int* __restrict__ src, const int* __restrict__ dst,
                          int* __restrict__ cursor, int* __restrict__ esrc, int E) {
    int e = blockIdx.x * blockDim.x + threadIdx.x;
    if (e < E) {
        int d = dst[e];
        int pos = atomicAdd(&cursor[d], 1);
        esrc[pos] = src[e];
    }
}

// ---------- LDS-staged MFMA GEMM + dinv pre-scale epilogue ----------
// xws[tile][row][col] = dinv[row] * (x@W)[row, tile*128+col]  (bf16)
__global__ __launch_bounds__(256) void k_gemm(const unsigned short* __restrict__ xb,
                                              const unsigned short* __restrict__ wtb,
                                              const float* __restrict__ dinv,
                                              unsigned short* __restrict__ xws,
                                              int N, int Mpad) {
    __shared__ unsigned short la[128 * LDA];
    __shared__ unsigned short lb[64 * LDA];

    const int bid = blockIdx.x;
    const int n0 = (bid & 7) * 64;
    const int m0 = (bid >> 3) * 128;
    const int tid = threadIdx.x;
    const int lane = tid & 63;
    const int wave = tid >> 6;
    const int wm = wave * 32;
    const int l15 = lane & 15;
    const int k8 = (lane >> 4) * 8;

    f32x4 acc[2][4];
#pragma unroll
    for (int t = 0; t < 2; ++t)
#pragma unroll
        for (int u = 0; u < 4; ++u)
            acc[t][u] = (f32x4){0.f, 0.f, 0.f, 0.f};

    for (int k0 = 0; k0 < INC; k0 += 64) {
#pragma unroll
        for (int i = 0; i < 4; ++i) {
            int f = i * 256 + tid;
            int row = f >> 3, c = f & 7;
            uint4 v = *(const uint4*)(xb + (size_t)(m0 + row) * INC + k0 + c * 8);
            *(uint4*)(&la[row * LDA + c * 8]) = v;
        }
#pragma unroll
        for (int i = 0; i < 2; ++i) {
            int f = i * 256 + tid;
            int row = f >> 3, c = f & 7;
            uint4 v = *(const uint4*)(wtb + (size_t)(n0 + row) * INC + k0 + c * 8);
            *(uint4*)(&lb[row * LDA + c * 8]) = v;
        }
        __syncthreads();

#pragma unroll
        for (int kc = 0; kc < 64; kc += 32) {
            bf16x8 af0 = *(const bf16x8*)(&la[(wm + l15) * LDA + kc + k8]);
            bf16x8 af1 = *(const bf16x8*)(&la[(wm + 16 + l15) * LDA + kc + k8]);
#pragma unroll
            for (int u = 0; u < 4; ++u) {
                bf16x8 bfr = *(const bf16x8*)(&lb[(u * 16 + l15) * LDA + kc + k8]);
                acc[0][u] = __builtin_amdgcn_mfma_f32_16x16x32_bf16(af0, bfr, acc[0][u], 0, 0, 0);
                acc[1][u] = __builtin_amdgcn_mfma_f32_16x16x32_bf16(af1, bfr, acc[1][u], 0, 0, 0);
            }
        }
        __syncthreads();
    }

    const int rbase = (lane >> 4) * 4;
    float ds[2][4];
#pragma unroll
    for (int t = 0; t < 2; ++t)
#pragma unroll
        for (int r = 0; r < 4; ++r) {
            int grow = m0 + wm + t * 16 + rbase + r;
            ds[t][r] = (grow < N) ? dinv[grow] : 0.f;  // pad rows: avoid poisoned dinv
        }
#pragma unroll
    for (int t = 0; t < 2; ++t)
#pragma unroll
        for (int u = 0; u < 4; ++u) {
            int gcol = n0 + u * 16 + l15;
            unsigned short* p = xws + (size_t)(gcol >> 7) * Mpad * TCOL + (gcol & 127);
#pragma unroll
            for (int r = 0; r < 4; ++r) {
                int grow = m0 + wm + t * 16 + rbase + r;
                p[(size_t)grow * TCOL] = f2bf(ds[t][r] * acc[t][u][r]);
            }
        }
}

// ---------- gather v2: 4 edges per wave-instruction ----------
// wave = one (node, tile). lane: slot=lane>>4 (edge), octet=lane&15 (8 cols, uint4).
// out[d] = dinv[d] * (sum_{s in N(d)} xws[s] + xws[d]) + temb
static __device__ __forceinline__ void acc8(float* a, uint4 v) {
    a[0] += bflo(v.x); a[1] += bfhi(v.x);
    a[2] += bflo(v.y); a[3] += bfhi(v.y);
    a[4] += bflo(v.z); a[5] += bfhi(v.z);
    a[6] += bflo(v.w); a[7] += bfhi(v.w);
}

__global__ __launch_bounds__(256) void k_gather(const int* __restrict__ esrc,
                                                const int* __restrict__ row_start,
                                                const unsigned short* __restrict__ XWS,
                                                const float* __restrict__ dinv,
                                                const float* __restrict__ temb,
                                                float* __restrict__ out, int N, int Mpad) {
    const int bid = blockIdx.x;
    const int tile = (bid & 7) >> 1;
    const int node = (bid >> 3) * 8 + (bid & 1) * 4 + (threadIdx.x >> 6);
    if (node >= N) return;
    const int lane = threadIdx.x & 63;
    const int slot = lane >> 4;
    const int c8 = (lane & 15) * 8;
    const unsigned short* base = XWS + (size_t)tile * Mpad * TCOL + c8;

    float a[8] = {0.f, 0.f, 0.f, 0.f, 0.f, 0.f, 0.f, 0.f};

    const int s0 = row_start[node];
    const int s1 = row_start[node + 1];
    int i = s0;
    // unrolled: 8 edges per iteration (2 row-load instrs in flight)
    for (; i + 8 <= s1; i += 8) {
        int sA = esrc[i + slot];
        int sB = esrc[i + 4 + slot];
        uint4 vA = *(const uint4*)(base + (size_t)sA * TCOL);
        uint4 vB = *(const uint4*)(base + (size_t)sB * TCOL);
        acc8(a, vA);
        acc8(a, vB);
    }
    // masked 4-edge tail groups
    for (; i < s1; i += 4) {
        int idx = i + slot;
        int s = (idx < s1) ? esrc[idx] : 0;
        uint4 v = *(const uint4*)(base + (size_t)s * TCOL);
        if (idx >= s1) { v.x = 0u; v.y = 0u; v.z = 0u; v.w = 0u; }
        acc8(a, v);
    }

    // reduce the 4 edge-slots (butterfly: all lanes end with the full sum)
#pragma unroll
    for (int k = 0; k < 8; ++k) {
        a[k] += __shfl_xor(a[k], 16, 64);
        a[k] += __shfl_xor(a[k], 32, 64);
    }

    // self-loop term (added once, post-reduce)
    {
        uint4 v = *(const uint4*)(base + (size_t)node * TCOL);
        acc8(a, v);
    }

    // scale + temb + store: slot 0 writes cols [c8, c8+4), slot 1 writes [c8+4, c8+8)
    if (slot < 2) {
        const float di = dinv[node];
        const int gc = tile * TCOL + c8 + slot * 4;
        float4 tv = *(const float4*)(temb + gc);
        float4 o;
        o.x = di * a[slot * 4 + 0] + tv.x;
        o.y = di * a[slot * 4 + 1] + tv.y;
        o.z = di * a[slot * 4 + 2] + tv.z;
        o.w = di * a[slot * 4 + 3] + tv.w;
        *(float4*)(out + (size_t)node * OUTC + gc) = o;
    }
}

extern "C" void kernel_launch(void* const* d_in, const int* in_sizes, int n_in,
                              void* d_out, int out_size, void* d_ws, size_t ws_size,
                              hipStream_t stream) {
    const float* x     = (const float*)d_in[0];
    const float* t_emb = (const float*)d_in[1];
    const int*   ei    = (const int*)d_in[2];
    const float* W     = (const float*)d_in[3];
    const float* b     = (const float*)d_in[4];
    const float* Wt    = (const float*)d_in[5];
    const float* bt    = (const float*)d_in[6];
    float* out = (float*)d_out;

    const int N  = in_sizes[0] / INC;    // 10000
    const int E  = in_sizes[2] / 2;      // 160000
    const int TC = in_sizes[1];          // 256
    const int Mpad = (N + 127) & ~127;   // 10112

    char* ws = (char*)d_ws;
    size_t off = 0;
    unsigned short* xb  = (unsigned short*)(ws + off); off += (size_t)Mpad * INC * 2;
    unsigned short* xws = (unsigned short*)(ws + off); off += (size_t)Mpad * OUTC * 2;
    unsigned short* wtb = (unsigned short*)(ws + off); off += (size_t)INC * OUTC * 2;
    float* dinv = (float*)(ws + off);      off += ((size_t)N * 4 + 255) & ~(size_t)255;
    int* counts = (int*)(ws + off);        off += ((size_t)N * 4 + 255) & ~(size_t)255;
    int* row_start = (int*)(ws + off);     off += ((size_t)(N + 1) * 4 + 255) & ~(size_t)255;
    int* cursor = (int*)(ws + off);        off += ((size_t)N * 4 + 255) & ~(size_t)255;
    int* esrc = (int*)(ws + off);          off += ((size_t)(E + 64) * 4 + 255) & ~(size_t)255;
    float* temb = (float*)(ws + off);      off += OUTC * 4;

    const int* srcIdx = ei;
    const int* dstIdx = ei + E;

    const int CB  = (E + 255) / 256;
    const int XBB = Mpad * (INC / 8) / 256;

    hipMemsetAsync(counts, 0, (size_t)N * sizeof(int), stream);
    k_prep<<<CB + XBB + 256 + OUTC, 256, 0, stream>>>(x, W, t_emb, Wt, bt, b, dstIdx,
                                                      counts, xb, wtb, temb,
                                                      E, CB, XBB, N, Mpad, TC);
    k_scan<<<1, SCAN_T, 0, stream>>>(counts, row_start, cursor, dinv, N);
    k_scatter<<<(E + 255) / 256, 256, 0, stream>>>(srcIdx, dstIdx, cursor, esrc, E);
    k_gemm<<<(Mpad / 128) * 8, 256, 0, stream>>>(xb, wtb, dinv, xws, N, Mpad);

    const int gather_blocks = ((N + 7) / 8) * 8;
    k_gather<<<gather_blocks, 256, 0, stream>>>(esrc, row_start, xws, dinv, temb, out, N, Mpad);
}